// Round 8
// baseline (186.595 us; speedup 1.0000x reference)
//
#include <hip/hip_runtime.h>
#include <hip/hip_bf16.h>

#define HEADS 8
#define HID 16
#define F1 128    // HEADS*HID
#define OUTD 64
#define XS_STRIDE 68   // padded LDS stride: 16B-aligned rows (68*4=272=17*16)
#define BWL 7          // log2(bucket width)
#define BW 128         // dst-range per bucket
#define MAXBUK 512     // >= ceil(N/BW); N=50000 -> 391
#define CHUNK 4096     // edges per block in count/scatter (256 thr x 16)

typedef unsigned int uint;
typedef unsigned short ushort;

__device__ __forceinline__ ushort f2bf(float f) {
  __hip_bfloat16 b = __float2bfloat16(f);
  return *reinterpret_cast<ushort*>(&b);
}
__device__ __forceinline__ float bf2f_lo(uint w) {
  return __uint_as_float((w & 0xFFFFu) << 16);
}
__device__ __forceinline__ float bf2f_hi(uint w) {
  return __uint_as_float(w & 0xFFFF0000u);
}

// ---------------- CSR build (bucket radix, low write-amplification) ----------------
// pairs packed: src in bits [0,20), dst&(BW-1) in bits [20,27). Requires N < 2^20.

__global__ void k_z(int* __restrict__ a, int n) {
  int i = blockIdx.x * blockDim.x + threadIdx.x;
  if (i < n) a[i] = 0;
}

__global__ __launch_bounds__(256) void k_bukcount(const int* __restrict__ ei, int E, int N,
                                                  int* __restrict__ bukcnt) {
  __shared__ int hist[MAXBUK];
  int t = threadIdx.x;
  hist[t] = 0; hist[t + 256] = 0;
  __syncthreads();
  long long e0 = (long long)blockIdx.x * CHUNK;
  int ET = E + N;
#pragma unroll
  for (int i = 0; i < 16; ++i) {
    long long e = e0 + i * 256 + t;
    if (e < ET) {
      int d = e < E ? ei[E + e] : (int)(e - E);
      atomicAdd(&hist[d >> BWL], 1);
    }
  }
  __syncthreads();
  for (int b = t; b < MAXBUK; b += 256)
    if (hist[b]) atomicAdd(&bukcnt[b], hist[b]);
}

__global__ __launch_bounds__(512) void k_bukscan(const int* __restrict__ bukcnt,
                                                 int* __restrict__ bukbase,
                                                 int* __restrict__ bukcur,
                                                 int* __restrict__ off,
                                                 int NBUK, int N, int ET) {
  __shared__ int sm[512];
  int t = threadIdx.x;
  int v = t < NBUK ? bukcnt[t] : 0;
  sm[t] = v;
  __syncthreads();
  for (int o = 1; o < 512; o <<= 1) {
    int u = t >= o ? sm[t - o] : 0;
    __syncthreads();
    sm[t] += u;
    __syncthreads();
  }
  if (t < NBUK) {
    int base = sm[t] - v;   // exclusive
    bukbase[t] = base;
    bukcur[t] = base;
  }
  if (t == 0) { bukbase[NBUK] = ET; off[N] = ET; }
}

__global__ __launch_bounds__(256) void k_scatter(const int* __restrict__ ei, int E, int N,
                                                 int* __restrict__ bukcur,
                                                 int* __restrict__ pairs) {
  __shared__ int hist[MAXBUK];
  int t = threadIdx.x;
  hist[t] = 0; hist[t + 256] = 0;
  __syncthreads();
  long long e0 = (long long)blockIdx.x * CHUNK;
  int ET = E + N;
  int myP[16], myB[16];
#pragma unroll
  for (int i = 0; i < 16; ++i) {
    long long e = e0 + i * 256 + t;
    if (e < ET) {
      int s = e < E ? ei[e] : (int)(e - E);
      int d = e < E ? ei[E + e] : (int)(e - E);
      myP[i] = s | ((d & (BW - 1)) << 20);
      myB[i] = d >> BWL;
      atomicAdd(&hist[myB[i]], 1);
    } else {
      myB[i] = -1;
    }
  }
  __syncthreads();
  for (int b = t; b < MAXBUK; b += 256) {
    int c = hist[b];
    hist[b] = c ? atomicAdd(&bukcur[b], c) : 0;
  }
  __syncthreads();
#pragma unroll
  for (int i = 0; i < 16; ++i) {
    if (myB[i] >= 0) {
      int pos = atomicAdd(&hist[myB[i]], 1);
      pairs[pos] = myP[i];
    }
  }
}

__global__ __launch_bounds__(256) void k_csr(const int* __restrict__ pairs,
                                             const int* __restrict__ bukbase,
                                             int* __restrict__ off, int* __restrict__ csr,
                                             int N) {
  __shared__ int cnt[BW];
  __shared__ int cur[BW];
  int b = blockIdx.x, t = threadIdx.x;
  int beg = bukbase[b], end = bukbase[b + 1];
  if (t < BW) cnt[t] = 0;
  __syncthreads();
  for (int j = beg + t; j < end; j += 256)
    atomicAdd(&cnt[(pairs[j] >> 20) & (BW - 1)], 1);
  __syncthreads();
  int my = t < BW ? cnt[t] : 0;
  for (int o = 1; o < BW; o <<= 1) {
    int v = (t < BW && t >= o) ? cnt[t - o] : 0;
    __syncthreads();
    if (t < BW) cnt[t] += v;
    __syncthreads();
  }
  if (t < BW) {
    int start = beg + cnt[t] - my;   // exclusive within bucket
    cur[t] = start;
    int d0 = b * BW + t;
    if (d0 < N) off[d0] = start;
  }
  __syncthreads();
  for (int j = beg + t; j < end; j += 256) {
    int pr = pairs[j];
    int pos = atomicAdd(&cur[(pr >> 20) & (BW - 1)], 1);
    csr[pos] = pr & 0xFFFFF;
  }
}

// ---------------- layer 1 GEMM ----------------
// 64 rows x 128 cols per block; 256 threads; thread owns 8 rows x 4 cols.
__global__ __launch_bounds__(256) void k_gemm1(
    const float* __restrict__ x, const float* __restrict__ W1,
    const float* __restrict__ as, const float* __restrict__ ad,
    uint* __restrict__ h1b, float* __restrict__ a_src,
    float* __restrict__ a_dst, int N) {
  __shared__ float xs[F1 * XS_STRIDE];   // xs[k][row], 34 KB
  int tx = threadIdx.x;
  int cg = tx & 31;          // col group: cols 4cg..4cg+3
  int rg = tx >> 5;          // row group: rows 8rg..8rg+7
  int r0 = blockIdx.x * 64;

  {
    int row = tx & 63, kq0 = tx >> 6;   // kq0 in [0,4)
#pragma unroll
    for (int it = 0; it < 8; ++it) {
      int k4 = (it * 4 + kq0) * 4;
      float4 v = make_float4(0.f, 0.f, 0.f, 0.f);
      if (r0 + row < N) v = *reinterpret_cast<const float4*>(&x[(size_t)(r0 + row) * F1 + k4]);
      xs[(k4 + 0) * XS_STRIDE + row] = v.x;
      xs[(k4 + 1) * XS_STRIDE + row] = v.y;
      xs[(k4 + 2) * XS_STRIDE + row] = v.z;
      xs[(k4 + 3) * XS_STRIDE + row] = v.w;
    }
  }
  __syncthreads();

  float acc[8][4];
#pragma unroll
  for (int i = 0; i < 8; ++i)
#pragma unroll
    for (int j = 0; j < 4; ++j) acc[i][j] = 0.f;

#pragma unroll 4
  for (int k = 0; k < F1; ++k) {
    float4 w = *reinterpret_cast<const float4*>(&W1[k * F1 + 4 * cg]);
    float4 xa = *reinterpret_cast<const float4*>(&xs[k * XS_STRIDE + rg * 8]);
    float4 xb = *reinterpret_cast<const float4*>(&xs[k * XS_STRIDE + rg * 8 + 4]);
    const float xr[8] = {xa.x, xa.y, xa.z, xa.w, xb.x, xb.y, xb.z, xb.w};
#pragma unroll
    for (int i = 0; i < 8; ++i) {
      acc[i][0] = fmaf(xr[i], w.x, acc[i][0]);
      acc[i][1] = fmaf(xr[i], w.y, acc[i][1]);
      acc[i][2] = fmaf(xr[i], w.z, acc[i][2]);
      acc[i][3] = fmaf(xr[i], w.w, acc[i][3]);
    }
  }

  float4 as4 = *reinterpret_cast<const float4*>(&as[4 * cg]);
  float4 ad4 = *reinterpret_cast<const float4*>(&ad[4 * cg]);
  int h = cg >> 2;
#pragma unroll
  for (int i = 0; i < 8; ++i) {
    int row = r0 + rg * 8 + i;
    bool act = row < N;
    if (act) {
      uint2 pk;
      pk.x = (uint)f2bf(acc[i][0]) | ((uint)f2bf(acc[i][1]) << 16);
      pk.y = (uint)f2bf(acc[i][2]) | ((uint)f2bf(acc[i][3]) << 16);
      *reinterpret_cast<uint2*>(&h1b[(size_t)row * 64 + 2 * cg]) = pk;
    }
    float ps = acc[i][0] * as4.x + acc[i][1] * as4.y + acc[i][2] * as4.z + acc[i][3] * as4.w;
    float pd = acc[i][0] * ad4.x + acc[i][1] * ad4.y + acc[i][2] * ad4.z + acc[i][3] * ad4.w;
    ps += __shfl_xor(ps, 1); ps += __shfl_xor(ps, 2);
    pd += __shfl_xor(pd, 1); pd += __shfl_xor(pd, 2);
    if (act && (cg & 3) == 0) {
      a_src[row * HEADS + h] = ps;
      a_dst[row * HEADS + h] = pd;
    }
  }
}

// ---------------- fused layer-1 aggregate + layer-2 GEMM ----------------
// 512 threads, 64 dsts/block. Phase A: 8 waves x 8 dsts, half-wave gather
// (R6 scheme); result+bias+ELU written straight into the transposed LDS
// tile (out1 never hits global). Phase B: gemm2 from LDS; writes h2b and
// scalar attention dots.
__global__ __launch_bounds__(512) void k_agg1g2(
    const int* __restrict__ off, const int* __restrict__ csr,
    const uint2* __restrict__ h1b2, const float* __restrict__ a_src,
    const float* __restrict__ a_dst, const float* __restrict__ b1,
    const float* __restrict__ W2, const float* __restrict__ as2,
    const float* __restrict__ ad2, uint* __restrict__ h2b,
    float* __restrict__ a_src2, float* __restrict__ a_dst2, int N) {
  __shared__ float xs[F1 * XS_STRIDE];   // elu(out1) tile, [k][row]
  int tx = threadIdx.x;
  int r0 = blockIdx.x * 64;

  // ---- phase A ----
  {
    int w = tx >> 6, lane = tx & 63;
    int half = lane >> 5, c2 = lane & 31, h = c2 >> 2;   // channels 4c2..4c2+3
    float4 bb = *reinterpret_cast<const float4*>(&b1[4 * c2]);
#pragma unroll
    for (int i = 0; i < 8; ++i) {
      int row = w * 8 + i;
      int d = r0 + row;
      if (d >= N) break;   // uniform per wave
      int beg = off[d], end = off[d + 1];
      float adl = a_dst[d * HEADS + h];
      float a0 = 0.f, a1 = 0.f, a2 = 0.f, a3 = 0.f, den = 0.f;
#pragma unroll 2
      for (int j = beg + half; j < end; j += 2) {
        int s = csr[j];
        float v = a_src[s * HEADS + h] + adl;
        v = v >= 0.f ? v : 0.2f * v;
        float p = __expf(v);
        uint2 wd = h1b2[(size_t)s * 32 + c2];
        a0 = fmaf(p, bf2f_lo(wd.x), a0);
        a1 = fmaf(p, bf2f_hi(wd.x), a1);
        a2 = fmaf(p, bf2f_lo(wd.y), a2);
        a3 = fmaf(p, bf2f_hi(wd.y), a3);
        den += p;
      }
      a0 += __shfl_xor(a0, 32);
      a1 += __shfl_xor(a1, 32);
      a2 += __shfl_xor(a2, 32);
      a3 += __shfl_xor(a3, 32);
      den += __shfl_xor(den, 32);
      if (half == 0) {
        float inv = 1.f / den;   // self-loop guarantees den > 0
        float o0 = a0 * inv + bb.x;
        float o1 = a1 * inv + bb.y;
        float o2 = a2 * inv + bb.z;
        float o3 = a3 * inv + bb.w;
        o0 = o0 > 0.f ? o0 : __expf(o0) - 1.f;
        o1 = o1 > 0.f ? o1 : __expf(o1) - 1.f;
        o2 = o2 > 0.f ? o2 : __expf(o2) - 1.f;
        o3 = o3 > 0.f ? o3 : __expf(o3) - 1.f;
        xs[(4 * c2 + 0) * XS_STRIDE + row] = o0;
        xs[(4 * c2 + 1) * XS_STRIDE + row] = o1;
        xs[(4 * c2 + 2) * XS_STRIDE + row] = o2;
        xs[(4 * c2 + 3) * XS_STRIDE + row] = o3;
      }
    }
  }
  __syncthreads();

  // ---- phase B: gemm2 (64 rows x 64 cols; thread owns 2 rows x 4 cols) ----
  int cg = tx & 15;          // cols 4cg..4cg+3
  int rg = tx >> 4;          // rows 2rg..2rg+1 (rg in [0,32))
  float acc[2][4];
#pragma unroll
  for (int i = 0; i < 2; ++i)
#pragma unroll
    for (int j = 0; j < 4; ++j) acc[i][j] = 0.f;

#pragma unroll 4
  for (int k = 0; k < F1; ++k) {
    float4 w = *reinterpret_cast<const float4*>(&W2[k * OUTD + 4 * cg]);
    float2 xv = *reinterpret_cast<const float2*>(&xs[k * XS_STRIDE + 2 * rg]);
    acc[0][0] = fmaf(xv.x, w.x, acc[0][0]);
    acc[0][1] = fmaf(xv.x, w.y, acc[0][1]);
    acc[0][2] = fmaf(xv.x, w.z, acc[0][2]);
    acc[0][3] = fmaf(xv.x, w.w, acc[0][3]);
    acc[1][0] = fmaf(xv.y, w.x, acc[1][0]);
    acc[1][1] = fmaf(xv.y, w.y, acc[1][1]);
    acc[1][2] = fmaf(xv.y, w.z, acc[1][2]);
    acc[1][3] = fmaf(xv.y, w.w, acc[1][3]);
  }

  float4 as4 = *reinterpret_cast<const float4*>(&as2[4 * cg]);
  float4 ad4 = *reinterpret_cast<const float4*>(&ad2[4 * cg]);
#pragma unroll
  for (int i = 0; i < 2; ++i) {
    int grow = r0 + 2 * rg + i;
    bool act = grow < N;
    if (act) {
      uint2 pk;
      pk.x = (uint)f2bf(acc[i][0]) | ((uint)f2bf(acc[i][1]) << 16);
      pk.y = (uint)f2bf(acc[i][2]) | ((uint)f2bf(acc[i][3]) << 16);
      *reinterpret_cast<uint2*>(&h2b[(size_t)grow * 32 + 2 * cg]) = pk;
    }
    float ps = acc[i][0] * as4.x + acc[i][1] * as4.y + acc[i][2] * as4.z + acc[i][3] * as4.w;
    float pd = acc[i][0] * ad4.x + acc[i][1] * ad4.y + acc[i][2] * ad4.z + acc[i][3] * ad4.w;
    ps += __shfl_xor(ps, 1); ps += __shfl_xor(ps, 2);
    ps += __shfl_xor(ps, 4); ps += __shfl_xor(ps, 8);
    pd += __shfl_xor(pd, 1); pd += __shfl_xor(pd, 2);
    pd += __shfl_xor(pd, 4); pd += __shfl_xor(pd, 8);
    if (act && cg == 0) {
      a_src2[grow] = ps;
      a_dst2[grow] = pd;
    }
  }
}

// ---------------- layer 2 aggregate ----------------
// 1 wave/dst; four 16-lane quarters process alternating edges; lane owns 4
// channels via uint2 loads; quarters combined with shfl_xor(16/32).
__global__ void k_agg2(const int* __restrict__ off, const int* __restrict__ csr,
                       const uint2* __restrict__ h2b2, const float* __restrict__ a_src2,
                       const float* __restrict__ a_dst2, const float* __restrict__ b2,
                       float* __restrict__ out, int N) {
  int w = threadIdx.x >> 6, lane = threadIdx.x & 63;
  int q = lane >> 4, c2 = lane & 15;   // channels 4c2..4c2+3
  int d = blockIdx.x * 4 + w;
  if (d >= N) return;
  int beg = off[d], end = off[d + 1];
  float adl = a_dst2[d];
  float a0 = 0.f, a1 = 0.f, a2 = 0.f, a3 = 0.f, den = 0.f;
#pragma unroll 2
  for (int j = beg + q; j < end; j += 4) {
    int s = csr[j];
    float v = a_src2[s] + adl;
    v = v >= 0.f ? v : 0.2f * v;
    float p = __expf(v);
    uint2 wd = h2b2[(size_t)s * 16 + c2];
    a0 = fmaf(p, bf2f_lo(wd.x), a0);
    a1 = fmaf(p, bf2f_hi(wd.x), a1);
    a2 = fmaf(p, bf2f_lo(wd.y), a2);
    a3 = fmaf(p, bf2f_hi(wd.y), a3);
    den += p;
  }
  a0 += __shfl_xor(a0, 16); a0 += __shfl_xor(a0, 32);
  a1 += __shfl_xor(a1, 16); a1 += __shfl_xor(a1, 32);
  a2 += __shfl_xor(a2, 16); a2 += __shfl_xor(a2, 32);
  a3 += __shfl_xor(a3, 16); a3 += __shfl_xor(a3, 32);
  den += __shfl_xor(den, 16); den += __shfl_xor(den, 32);
  if (q == 0) {
    float inv = 1.f / den;
    float4 bb = *reinterpret_cast<const float4*>(&b2[4 * c2]);
    float4 o;
    o.x = a0 * inv + bb.x;
    o.y = a1 * inv + bb.y;
    o.z = a2 * inv + bb.z;
    o.w = a3 * inv + bb.w;
    *reinterpret_cast<float4*>(&out[(size_t)d * OUTD + 4 * c2]) = o;
  }
}

extern "C" void kernel_launch(void* const* d_in, const int* in_sizes, int n_in,
                              void* d_out, int out_size, void* d_ws, size_t ws_size,
                              hipStream_t stream) {
  const float* x   = (const float*)d_in[0];
  const int*   ei  = (const int*)d_in[1];
  const float* W1  = (const float*)d_in[2];
  const float* as1 = (const float*)d_in[3];
  const float* ad1 = (const float*)d_in[4];
  const float* b1  = (const float*)d_in[5];
  const float* W2  = (const float*)d_in[6];
  const float* as2 = (const float*)d_in[7];
  const float* ad2 = (const float*)d_in[8];
  const float* b2  = (const float*)d_in[9];
  float* out = (float*)d_out;

  int N = in_sizes[0] / F1;
  int E = in_sizes[1] / 2;
  int ET = E + N;
  int NBUK = (N + BW - 1) / BW;       // 391 for N=50000 (<= MAXBUK)
  int NCH = (ET + CHUNK - 1) / CHUNK; // count/scatter blocks
  int NT = (N + 63) / 64;             // tile count (gemm1 / fused)

  // workspace layout (16B-aligned chunks). NOTE: layer-2 buffers must NOT
  // alias layer-1 buffers anymore — the fused kernel writes h2b/a_*2 while
  // other blocks still read h1b/a_*1.
  char* p = (char*)d_ws;
  auto alloc = [&](size_t bytes) {
    char* q = p;
    p += (bytes + 15) & ~(size_t)15;
    return q;
  };
  int* bukcnt  = (int*)alloc((size_t)NBUK * 4);
  int* bukbase = (int*)alloc((size_t)(NBUK + 1) * 4);
  int* bukcur  = (int*)alloc((size_t)NBUK * 4);
  int* off     = (int*)alloc((size_t)(N + 1) * 4);
  int* pairs   = (int*)alloc((size_t)ET * 4);
  int* csr     = (int*)alloc((size_t)ET * 4);
  uint* h1b    = (uint*)alloc((size_t)N * 64 * 4);
  uint* h2b    = (uint*)alloc((size_t)N * 32 * 4);
  float* a_src1 = (float*)alloc((size_t)N * HEADS * 4);
  float* a_dst1 = (float*)alloc((size_t)N * HEADS * 4);
  float* a_src2 = (float*)alloc((size_t)N * 4);
  float* a_dst2 = (float*)alloc((size_t)N * 4);

  // CSR build (shared by both layers)
  hipLaunchKernelGGL(k_z, dim3((NBUK + 255) / 256), dim3(256), 0, stream, bukcnt, NBUK);
  hipLaunchKernelGGL(k_bukcount, dim3(NCH), dim3(256), 0, stream, ei, E, N, bukcnt);
  hipLaunchKernelGGL(k_bukscan, dim3(1), dim3(512), 0, stream,
                     bukcnt, bukbase, bukcur, off, NBUK, N, ET);
  hipLaunchKernelGGL(k_scatter, dim3(NCH), dim3(256), 0, stream, ei, E, N, bukcur, pairs);
  hipLaunchKernelGGL(k_csr, dim3(NBUK), dim3(256), 0, stream, pairs, bukbase, off, csr, N);

  // layer 1 GEMM
  hipLaunchKernelGGL(k_gemm1, dim3(NT), dim3(256), 0, stream,
                     x, W1, as1, ad1, h1b, a_src1, a_dst1, N);

  // fused layer-1 aggregate + layer-2 GEMM
  hipLaunchKernelGGL(k_agg1g2, dim3(NT), dim3(512), 0, stream,
                     off, csr, (const uint2*)h1b, a_src1, a_dst1, b1,
                     W2, as2, ad2, h2b, a_src2, a_dst2, N);

  // layer 2 aggregate
  hipLaunchKernelGGL(k_agg2, dim3((N + 3) / 4), dim3(256), 0, stream,
                     off, csr, (const uint2*)h2b, a_src2, a_dst2, b2, out, N);
}